// Round 1
// baseline (2346.489 us; speedup 1.0000x reference)
//
#include <hip/hip_runtime.h>

// GPConv3D: Cl(3,0) geometric-product 3D convolution.
// out[b,o,k,d,h,w] = sum_{i,j,c,m,l,v} G[i,j,k] x[b,c,i,d+m,h+l,w+v] W[m,l,v,c,o,j] + bias[o,k]
// G[i,j,k] nonzero only at k = i^j with sign = Cayley reorder parity (euclidean
// metric), so we skip the G input entirely and fold sign(i,j) into FMA modifiers
// at compile time via full unroll of the 8x8 (i,j) microkernel.

namespace {

constexpr int CIN = 8, COUT = 8, BD = 8, DIN = 48, DOUT = 46;
constexpr int XI_STRIDE = DIN * DIN * DIN;   // 110592: stride between basis blades of x
constexpr int OUT_SP    = DOUT * DOUT * DOUT; // 97336

__host__ __device__ constexpr int popc_(int v) { int c = 0; while (v) { c += v & 1; v >>= 1; } return c; }
// sign such that e_a * e_b = sign * e_{a^b}  (euclidean Cl(3,0))
__host__ __device__ constexpr float ga_sign(int a, int b) {
  int s = 0;
  for (int t = a >> 1; t; t >>= 1) s += popc_(t & b);
  return (s & 1) ? -1.0f : 1.0f;
}

// Block: one (d, b, o-half). 256 threads sweep the 46x46 (h,w) plane.
// Per thread per position: acc[4 o][8 k]; inner (c, m, l, v) loop does
// 8 vector x loads + 32 uniform W loads + 256 FMAs.
__global__ __launch_bounds__(256) void gpconv_kernel(
    const float* __restrict__ x,     // [8, 8, 8, 48, 48, 48]
    const float* __restrict__ Wt,    // [3, 3, 3, 8, 8, 8] (m,l,v,c,o,j)
    const float* __restrict__ bias,  // [8, 8] (o,k)
    float* __restrict__ out)         // [8, 8, 8, 46, 46, 46]
{
  const int d  = blockIdx.x;       // 0..45
  const int b  = blockIdx.y;       // 0..7
  const int o0 = blockIdx.z * 4;   // {0,4}

  const float* xb = x + (size_t)b * (CIN * BD * XI_STRIDE);

  for (int hw = threadIdx.x; hw < DOUT * DOUT; hw += 256) {
    const int h = hw / DOUT;
    const int w = hw - h * DOUT;

    float acc[4][8];
#pragma unroll
    for (int ol = 0; ol < 4; ++ol)
#pragma unroll
      for (int k = 0; k < 8; ++k) acc[ol][k] = 0.0f;

#pragma unroll 1
    for (int c = 0; c < CIN; ++c) {
      const float* xc = xb + c * (BD * XI_STRIDE) + d * (DIN * DIN) + h * DIN + w;
#pragma unroll 1
      for (int m = 0; m < 3; ++m) {
#pragma unroll 1
        for (int l = 0; l < 3; ++l) {
          const float* xr = xc + m * (DIN * DIN) + l * DIN;
#pragma unroll 1
          for (int v = 0; v < 3; ++v) {
            float xi[8];
#pragma unroll
            for (int i = 0; i < 8; ++i) xi[i] = xr[v + i * XI_STRIDE];
            // W[m,l,v,c,o,j]: offset = (((m*3+l)*3+v)*8 + c)*64 + o*8 + j  (uniform -> s_load)
            const float* wp = Wt + ((((m * 3 + l) * 3 + v) * CIN) + c) * (COUT * BD) + o0 * BD;
#pragma unroll
            for (int ol = 0; ol < 4; ++ol) {
#pragma unroll
              for (int j = 0; j < 8; ++j) {
                const float wj = wp[ol * 8 + j];
#pragma unroll
                for (int i = 0; i < 8; ++i)
                  acc[ol][i ^ j] = fmaf(ga_sign(i, j) * xi[i], wj, acc[ol][i ^ j]);
              }
            }
          }
        }
      }
    }

    // out offset = (b*8+o)*8*97336 + k*97336 + d*2116 + hw
    const size_t obase = ((size_t)(b * COUT + o0) * BD) * OUT_SP + (size_t)d * (DOUT * DOUT) + hw;
#pragma unroll
    for (int ol = 0; ol < 4; ++ol)
#pragma unroll
      for (int k = 0; k < 8; ++k)
        out[obase + ((size_t)ol * BD + k) * OUT_SP] = acc[ol][k] + bias[(o0 + ol) * BD + k];
  }
}

}  // namespace

extern "C" void kernel_launch(void* const* d_in, const int* in_sizes, int n_in,
                              void* d_out, int out_size, void* d_ws, size_t ws_size,
                              hipStream_t stream) {
  const float* x    = (const float*)d_in[0];
  const float* W    = (const float*)d_in[1];
  const float* bias = (const float*)d_in[2];
  // d_in[3] (G table) intentionally unused: structure hardcoded via ga_sign.
  float* out = (float*)d_out;

  dim3 grid(DOUT, 8, 2);  // (d, b, o-half) = 736 blocks x 256 threads
  gpconv_kernel<<<grid, 256, 0, stream>>>(x, W, bias, out);
}

// Round 2
// 568.667 us; speedup vs baseline: 4.1263x; 4.1263x over previous
//
#include <hip/hip_runtime.h>

// GPConv3D as implicit GEMM on bf16 MFMA.
// out[(o,k)][(b,d,h,w)] = sum_{m,l,v,c,i} ga_sign(i,i^k) W[m,l,v,c,o,i^k] * x[b,c,i,d+m,h+l,w+v] + bias
// M=64 (o*8+k), K=1728 = 27 taps x 64 (c*8+i), N=8*46^3.
// A is pre-packed (sign-folded, bf16, MFMA-fragment order) in d_ws; x converted to bf16 in d_ws.
// Main kernel: block = 4 waves, wave = M64 x 48w-row (wh = wave id), per (m,l) tap the staged
// 48-wide rows serve all 3 v-shifts via LDS column offset.

namespace {

constexpr int DIN = 48, DOUT = 46;
constexpr size_t X_ELEMS = 8ull * 8 * 8 * DIN * DIN * DIN;   // 56,623,104
constexpr size_t XBF_BYTES = X_ELEMS * 2;                    // 113,246,208
constexpr int APK_ELEMS = 54 * 4 * 64 * 8;                   // 110,592 bf16
constexpr int KPITCH = 40;                                   // LDS k-pitch (pad 32->40)

__host__ __device__ constexpr int popc_(int v) { int c = 0; while (v) { c += v & 1; v >>= 1; } return c; }
__host__ __device__ inline float ga_sign(int a, int b) {
  int s = 0;
  for (int t = a >> 1; t; t >>= 1) s += popc_(t & b);
  return (s & 1) ? -1.0f : 1.0f;
}

__device__ inline unsigned short f2bf(float f) {  // round-to-nearest-even
  unsigned u = __builtin_bit_cast(unsigned, f);
  u += 0x7fffu + ((u >> 16) & 1u);
  return (unsigned short)(u >> 16);
}

using frag  = __attribute__((ext_vector_type(8))) short;  // 8 bf16 (4 VGPRs)
using f32x4 = __attribute__((ext_vector_type(4))) float;

// ---- prep 1: x fp32 -> bf16 (RNE), 8 elems/thread ----
__global__ __launch_bounds__(256) void cvt_x(const float* __restrict__ x,
                                             unsigned short* __restrict__ xbf, int n8) {
  int t = blockIdx.x * 256 + threadIdx.x;
  if (t >= n8) return;
  const float4* xp = (const float4*)x;
  float4 f0 = xp[2 * t], f1 = xp[2 * t + 1];
  union { unsigned short us[8]; uint4 u4; } p;
  p.us[0] = f2bf(f0.x); p.us[1] = f2bf(f0.y); p.us[2] = f2bf(f0.z); p.us[3] = f2bf(f0.w);
  p.us[4] = f2bf(f1.x); p.us[5] = f2bf(f1.y); p.us[6] = f2bf(f1.z); p.us[7] = f2bf(f1.w);
  ((uint4*)xbf)[t] = p.u4;
}

// ---- prep 2: pack A (sign-folded weights) into MFMA fragment order ----
// Apk[e], e = ((s*4+q)*64 + mi)*8 + t ; K-step s = ((m*3+l)*3+v)*2 + cb ; k_local = q*8+t
__global__ __launch_bounds__(256) void build_apk(const float* __restrict__ W,
                                                 unsigned short* __restrict__ Apk) {
  int e = blockIdx.x * 256 + threadIdx.x;  // < 110592
  int t  = e & 7;
  int mi = (e >> 3) & 63;
  int q  = (e >> 9) & 3;
  int s  = e >> 11;                 // 0..53
  int cb = s & 1, mlv = s >> 1;
  int v = mlv % 3, l = (mlv / 3) % 3, m = mlv / 9;
  int kl = cb * 32 + q * 8 + t;     // (c,i)
  int c = kl >> 3, i = kl & 7;
  int o = mi >> 3, kb = mi & 7, j = i ^ kb;
  float val = ga_sign(i, j) * W[((((m * 3 + l) * 3 + v) * 8 + c) * 8 + o) * 8 + j];
  Apk[e] = f2bf(val);
}

// ---- main: implicit GEMM ----
__global__ __launch_bounds__(256) void gpconv_mfma(
    const unsigned short* __restrict__ xbf,  // [8,8,8,48,48,48] bf16
    const unsigned short* __restrict__ Apk,  // packed A frags
    const float* __restrict__ bias,          // [64]
    float* __restrict__ out)                 // [8,64,46,46,46]
{
  const int d = blockIdx.x, hg = blockIdx.y, b = blockIdx.z;
  const int h0 = hg * 4;
  const int tid = threadIdx.x;
  const int wh = tid >> 6;          // wave id = output h row offset
  const int lane = tid & 63, r = lane & 15, q = lane >> 4;

  __shared__ __attribute__((aligned(16))) short Xs[6][50 * KPITCH];

  // zero pad columns n=48,49 (read by masked outputs only; avoid NaN-from-uninit)
  for (int z = tid; z < 6 * 2 * KPITCH; z += 256) {
    int s6 = z / (2 * KPITCH), rem = z % (2 * KPITCH);
    Xs[s6][(48 + rem / KPITCH) * KPITCH + rem % KPITCH] = 0;
  }

  // staging constants: tid<192 -> kg=tid/24 (k-row group of 4), dwi (dword-of-48-row)
  const int kg = tid / 24;
  const int dwi = tid - kg * 24;
  const bool stager = tid < 192;

  f32x4 acc[4][3];
#pragma unroll
  for (int ms = 0; ms < 4; ++ms)
#pragma unroll
    for (int nt = 0; nt < 3; ++nt) acc[ms][nt] = (f32x4){0.f, 0.f, 0.f, 0.f};

#pragma unroll 1
  for (int m = 0; m < 3; ++m) {
    const int zin = d + m;
#pragma unroll 1
    for (int cb = 0; cb < 2; ++cb) {
      __syncthreads();
      if (stager) {
#pragma unroll
        for (int s6 = 0; s6 < 6; ++s6) {
          const int y = h0 + s6;  // may reach 49 at hg=11: over-read stays inside d_ws (Apk region), outputs masked
          unsigned u[4];
#pragma unroll
          for (int jj = 0; jj < 4; ++jj) {
            const int row = kg * 4 + jj;                       // k_local in [0,32)
            const int ci = (b * 8 + cb * 4 + (row >> 3)) * 8 + (row & 7);
            const size_t gidx = ((size_t)(ci * 48 + zin) * 48 + y) * 48 + dwi * 2;
            u[jj] = *(const unsigned*)(xbf + gidx);
          }
          uint2 lo, hi;  // transpose 4k x 2n
          lo.x = (u[0] & 0xffffu) | (u[1] << 16);
          lo.y = (u[2] & 0xffffu) | (u[3] << 16);
          hi.x = (u[0] >> 16) | (u[1] & 0xffff0000u);
          hi.y = (u[2] >> 16) | (u[3] & 0xffff0000u);
          *(uint2*)&Xs[s6][(2 * dwi) * KPITCH + kg * 4] = lo;
          *(uint2*)&Xs[s6][(2 * dwi + 1) * KPITCH + kg * 4] = hi;
        }
      }
      __syncthreads();
#pragma unroll
      for (int l = 0; l < 3; ++l) {
#pragma unroll
        for (int v = 0; v < 3; ++v) {
          const int s = ((m * 3 + l) * 3 + v) * 2 + cb;
          frag a[4], bf[3];
#pragma unroll
          for (int ms = 0; ms < 4; ++ms)
            a[ms] = *(const frag*)(Apk + (size_t)((s * 4 + q) * 64 + ms * 16 + r) * 8);
#pragma unroll
          for (int nt = 0; nt < 3; ++nt)
            bf[nt] = *(const frag*)&Xs[l + wh][(nt * 16 + r + v) * KPITCH + q * 8];
#pragma unroll
          for (int ms = 0; ms < 4; ++ms)
#pragma unroll
            for (int nt = 0; nt < 3; ++nt)
              acc[ms][nt] = __builtin_amdgcn_mfma_f32_16x16x32_bf16(a[ms], bf[nt], acc[ms][nt], 0, 0, 0);
        }
      }
    }
  }

  // epilogue: D[row=q*4+reg][col=r] per 16x16 subtile
  const int y = h0 + wh;
  if (y < DOUT) {
#pragma unroll
    for (int ms = 0; ms < 4; ++ms) {
#pragma unroll
      for (int nt = 0; nt < 3; ++nt) {
        const int w = nt * 16 + r;
        if (w < DOUT) {
#pragma unroll
          for (int reg = 0; reg < 4; ++reg) {
            const int mrow = ms * 16 + q * 4 + reg;  // o*8+k
            const size_t oidx = (((size_t)(b * 64 + mrow) * DOUT + d) * DOUT + y) * DOUT + w;
            out[oidx] = acc[ms][nt][reg] + bias[mrow];
          }
        }
      }
    }
  }
}

}  // namespace

extern "C" void kernel_launch(void* const* d_in, const int* in_sizes, int n_in,
                              void* d_out, int out_size, void* d_ws, size_t ws_size,
                              hipStream_t stream) {
  const float* x    = (const float*)d_in[0];
  const float* W    = (const float*)d_in[1];
  const float* bias = (const float*)d_in[2];
  float* out = (float*)d_out;

  unsigned short* xbf = (unsigned short*)d_ws;
  unsigned short* Apk = (unsigned short*)((char*)d_ws + XBF_BYTES);

  const int n8 = (int)(X_ELEMS / 8);                     // 7,077,888
  cvt_x<<<n8 / 256, 256, 0, stream>>>(x, xbf, n8);       // 27,648 blocks
  build_apk<<<APK_ELEMS / 256, 256, 0, stream>>>(W, Apk);

  dim3 grid(DOUT, 12, 8);  // (d, h-group of 4, b) = 4416 blocks
  gpconv_mfma<<<grid, 256, 0, stream>>>(xbf, Apk, bias, out);
}